// Round 9
// baseline (50.759 us; speedup 1.0000x reference)
//
#include <hip/hip_runtime.h>

typedef _Float16 f16;
typedef __attribute__((ext_vector_type(2))) __fp16 fp16x2;
typedef __attribute__((ext_vector_type(8))) _Float16 f16x8;
typedef __attribute__((ext_vector_type(4))) float f32x4;
typedef __attribute__((ext_vector_type(4))) unsigned int u32x4;

#define NPTS   (16 * 32768)
// packed-weight layout in d_ws (bytes); weights stay in global (L2-resident, ~80KB)
#define W0P_OFF 0
#define W1P_OFF (16 * 1024)
#define W2P_OFF (48 * 1024)
#define WOP_OFF (80 * 1024)
#define FRAGS_BYTES (84 * 1024)
#define TENC_OFF FRAGS_BYTES          // in ws: 16 batches x 16 f32
#define WS_NEEDED (FRAGS_BYTES + 1024)
// LDS: only per-wave transpose scratch. 8 waves x 4KB = 32KB/block.
#define LDS_TOTAL (8 * 4096)

// ---------------- pack kernel: weights -> f16 A-operand fragments (W^T) ----------------
// A frag (mt,kt): lane l, elem j <-> W_sw[m = 16mt + (l&15)][k] = W[k][m]
//   layer0 (natural k-map, matches layer-0 B build): k = 32kt + 8*(l>>4) + j
//   layers 1,2,out (chained from D layout):          k = 32kt + 16*(j>>2) + 4*(l>>4) + (j&3)
__global__ void pack_weights(const float* __restrict__ time, const float* __restrict__ te0,
                             const float* __restrict__ te1, const float* __restrict__ W0,
                             const float* __restrict__ W1, const float* __restrict__ W2,
                             const float* __restrict__ Wout, unsigned char* __restrict__ ws) {
  const int bi = blockIdx.x;
  const int l = threadIdx.x;
  const int g = l >> 4, r16 = l & 15;
  if (bi < 84) {
    const float* W; int obase, fi, kt, mt, kmax; bool natural, outcol;
    if (bi < 16)      { W = W0;   fi = bi;      mt = fi >> 1; kt = fi & 1; obase = W0P_OFF; kmax = 55;  natural = true;  outcol = false; }
    else if (bi < 48) { W = W1;   fi = bi - 16; mt = fi >> 2; kt = fi & 3; obase = W1P_OFF; kmax = 128; natural = false; outcol = false; }
    else if (bi < 80) { W = W2;   fi = bi - 48; mt = fi >> 2; kt = fi & 3; obase = W2P_OFF; kmax = 128; natural = false; outcol = false; }
    else              { W = Wout; fi = bi - 80; mt = 0;       kt = fi;     obase = WOP_OFF; kmax = 128; natural = false; outcol = true;  }
    const int m = mt * 16 + r16;
    f16 vals[8] __attribute__((aligned(16)));
#pragma unroll
    for (int j = 0; j < 8; ++j) {
      const int k = natural ? (kt * 32 + g * 8 + j)
                            : (kt * 32 + (j >> 2) * 16 + g * 4 + (j & 3));
      float v = 0.f;
      if (k < kmax) v = outcol ? ((m == 0) ? Wout[k] : 0.f) : W[k * 128 + m];
      vals[j] = (f16)v;
    }
    *(u32x4*)(ws + obase + (fi * 64 + l) * 16) = *(const u32x4*)vals;
  } else {
    // time encoding: 16 batches x 16 dims fp32
    const int idx = (bi - 84) * 64 + l;  // 0..255
    const int b = idx >> 4, d = idx & 15;
    const float t = time[b];
    const float* emb; int L, dd;
    if (d < 8) { emb = te0; L = 5;  dd = d; }
    else       { emb = te1; L = 20; dd = d - 8; }
    const float tL = t * (float)L;
    int i = (int)floorf(tL);
    i = i < 0 ? 0 : (i > L - 1 ? L - 1 : i);
    const float wlo = (float)(i + 1) - tL;
    float v = wlo * emb[i * 8 + dd] + (1.f - wlo) * emb[(i + 1) * 8 + dd];
    if (t >= 1.f) v = emb[L * 8 + dd];
    ((float*)(ws + TENC_OFF))[idx] = v;
  }
}

// ---------------- one swapped hidden layer: D = W_sw(128xK) * Bin(Kx64) ----------------
// Quad-row steps: each step loads 4 A-frags (64 output rows) and issues 16 MFMAs
// (~78 pipe-cycles), doubling per-wave MFMA density per load-latency window vs the
// 8-MFMA step. 2-deep rotating prefetch over the flattened (q,kt) sequence ->
// ~160+ cycles of cover for the ~200-250 cyc L2 latency. One epilogue per quad.
template <int KT>
__device__ __forceinline__ void layer_swapped(const unsigned char* __restrict__ wsrc,
                                              const float* __restrict__ bias,
                                              const f16x8 (&Bin)[KT][4], f16x8 (&Bout)[4][4],
                                              int lane) {
  const int g4 = (lane >> 4) * 4;
  f16x8 Ab[3][4];
  // prologue: preload steps 0,1  (step s: quad q = s/KT, kt = s%KT; frag mt = 4q+m)
#pragma unroll
  for (int s = 0; s < 2; ++s) {
    const int q = s / KT, kt = s % KT;
#pragma unroll
    for (int m = 0; m < 4; ++m)
      Ab[s][m] = *(const f16x8*)(wsrc + (((4 * q + m) * KT + kt) * 64 + lane) * 16);
  }
#pragma unroll
  for (int q = 0; q < 2; ++q) {
    float4 bv[4];
#pragma unroll
    for (int i = 0; i < 4; ++i)
      bv[i] = *(const float4*)(bias + q * 64 + i * 16 + g4);
    f32x4 acc[4][4];
#pragma unroll
    for (int m = 0; m < 4; ++m)
#pragma unroll
      for (int nt = 0; nt < 4; ++nt) acc[m][nt] = (f32x4){0.f, 0.f, 0.f, 0.f};
#pragma unroll
    for (int kt = 0; kt < KT; ++kt) {
      const int s = q * KT + kt, cb = s % 3;
      // prefetch step s+2
      if (s + 2 < 2 * KT) {
        const int q2 = (s + 2) / KT, kt2 = (s + 2) % KT, pb = (s + 2) % 3;
#pragma unroll
        for (int m = 0; m < 4; ++m)
          Ab[pb][m] = *(const f16x8*)(wsrc + (((4 * q2 + m) * KT + kt2) * 64 + lane) * 16);
      }
      __builtin_amdgcn_s_setprio(1);
#pragma unroll
      for (int m = 0; m < 4; ++m)
#pragma unroll
        for (int nt = 0; nt < 4; ++nt)
          acc[m][nt] = __builtin_amdgcn_mfma_f32_16x16x32_f16(Ab[cb][m], Bin[kt][nt], acc[m][nt], 0, 0, 0);
      __builtin_amdgcn_s_setprio(0);
    }
    // epilogue once per quad: Bout[2q+h][nt] from acc[2h]/acc[2h+1] + bias
#pragma unroll
    for (int h = 0; h < 2; ++h) {
      const float* bap = (const float*)&bv[2 * h];
      const float* bbp = (const float*)&bv[2 * h + 1];
#pragma unroll
      for (int nt = 0; nt < 4; ++nt) {
        union { fp16x2 h2[4]; f16x8 v; } u;
        u.h2[0] = __builtin_amdgcn_cvt_pkrtz(fmaxf(acc[2*h][nt][0] + bap[0], 0.f), fmaxf(acc[2*h][nt][1] + bap[1], 0.f));
        u.h2[1] = __builtin_amdgcn_cvt_pkrtz(fmaxf(acc[2*h][nt][2] + bap[2], 0.f), fmaxf(acc[2*h][nt][3] + bap[3], 0.f));
        u.h2[2] = __builtin_amdgcn_cvt_pkrtz(fmaxf(acc[2*h+1][nt][0] + bbp[0], 0.f), fmaxf(acc[2*h+1][nt][1] + bbp[1], 0.f));
        u.h2[3] = __builtin_amdgcn_cvt_pkrtz(fmaxf(acc[2*h+1][nt][2] + bbp[2], 0.f), fmaxf(acc[2*h+1][nt][3] + bbp[3], 0.f));
        Bout[2 * q + h][nt] = u.v;
      }
    }
  }
}

// ---------------- fused main kernel: 512 thr, weights from L2, quad-row pipelined ----------------
// __launch_bounds__(512,1): VGPR budget 2048/8 = 256 (law: (256,1)->180, (512,2)->128,
// (1024,*)->64). Live set ~230 fits; FETCH_SIZE ~3.5MB is the no-spill tripwire.
__global__ void __launch_bounds__(512, 1)
mlp_main(const float* __restrict__ xyz, const float* __restrict__ b0,
         const float* __restrict__ b1, const float* __restrict__ b2,
         const float* __restrict__ bout, const unsigned char* __restrict__ ws,
         float* __restrict__ out) {
  extern __shared__ char lds[];
  const int tid = threadIdx.x;
  const int lane = tid & 63, wv = tid >> 6;
  const int g = lane >> 4, r16 = lane & 15;

  char* scr = lds + wv * 4096;  // per-wave private transpose scratch (32 rows x 128B)
  const float bo = bout[0];

  const int pbase = blockIdx.x * 512 + wv * 64;
  const int p = pbase + lane;

  // ---- 64-dim feature row for own point ----
  f16 feat[64] __attribute__((aligned(16)));
  const float* tb = (const float*)(ws + TENC_OFF) + (blockIdx.x >> 6) * 16;  // batch = p/32768
#pragma unroll
  for (int i = 0; i < 16; ++i) feat[i] = (f16)tb[i];
  const float xs0 = xyz[p * 3], xs1 = xyz[p * 3 + 1], xs2 = xyz[p * 3 + 2];
  const float pcs[3] = {(xs0 + 1.f) * 0.5f, (xs1 + 1.f) * 0.5f, (xs2 + 1.f) * 0.5f};
#pragma unroll
  for (int c = 0; c < 3; ++c) {
    feat[16 + c] = (f16)pcs[c];
    float s = __sinf(pcs[c]), co = __cosf(pcs[c]);
#pragma unroll
    for (int f = 0; f < 6; ++f) {
      feat[19 + f * 3 + c] = (f16)s;
      feat[37 + f * 3 + c] = (f16)co;
      const float s2 = 2.f * s * co, c2 = 1.f - 2.f * s * s;
      s = s2; co = c2;
    }
  }
#pragma unroll
  for (int i = 55; i < 64; ++i) feat[i] = (f16)0.f;

  // ---- transpose via per-wave scratch, two 32-point halves (wave-internal sync) ----
  f16x8 B0[2][4];
#pragma unroll
  for (int h = 0; h < 2; ++h) {
    if ((lane >> 5) == h) {
#pragma unroll
      for (int s = 0; s < 8; ++s)
        *(u32x4*)(scr + (lane & 31) * 128 + ((s ^ (lane & 7)) * 16)) = ((const u32x4*)feat)[s];
    }
    asm volatile("s_waitcnt lgkmcnt(0)" ::: "memory");
#pragma unroll
    for (int kt = 0; kt < 2; ++kt)
#pragma unroll
      for (int nn = 0; nn < 2; ++nn) {
        const int row = nn * 16 + r16;
        B0[kt][h * 2 + nn] = *(const f16x8*)(scr + row * 128 + (((4 * kt + g) ^ (row & 7)) * 16));
      }
    asm volatile("s_waitcnt lgkmcnt(0)" ::: "memory");
  }

  // ---- 3 hidden layers fully in registers, weights streamed from L2 w/ prefetch ----
  f16x8 Bx[4][4], By[4][4];
  layer_swapped<2>(ws + W0P_OFF, b0, B0, Bx, lane);
  layer_swapped<4>(ws + W1P_OFF, b1, Bx, By, lane);
  layer_swapped<4>(ws + W2P_OFF, b2, By, Bx, lane);

  // ---- output layer (M=16 padded, only row 0 real), rotating prefetch ----
  f16x8 Ab[3];
  Ab[0] = *(const f16x8*)(ws + WOP_OFF + (0 * 64 + lane) * 16);
  Ab[1] = *(const f16x8*)(ws + WOP_OFF + (1 * 64 + lane) * 16);
  f32x4 accO[4];
#pragma unroll
  for (int nt = 0; nt < 4; ++nt) accO[nt] = (f32x4){bo, bo, bo, bo};
#pragma unroll
  for (int kt = 0; kt < 4; ++kt) {
    if (kt + 2 < 4)
      Ab[(kt + 2) % 3] = *(const f16x8*)(ws + WOP_OFF + ((kt + 2) * 64 + lane) * 16);
    __builtin_amdgcn_s_setprio(1);
#pragma unroll
    for (int nt = 0; nt < 4; ++nt)
      accO[nt] = __builtin_amdgcn_mfma_f32_16x16x32_f16(Ab[kt % 3], Bx[kt][nt], accO[nt], 0, 0, 0);
    __builtin_amdgcn_s_setprio(0);
  }

  // ---- coalesced store: broadcast row-0 values, one 256B wave store ----
  const float a0 = __shfl(accO[0][0], r16, 64);
  const float a1 = __shfl(accO[1][0], r16, 64);
  const float a2 = __shfl(accO[2][0], r16, 64);
  const float a3 = __shfl(accO[3][0], r16, 64);
  const float v = g == 0 ? a0 : g == 1 ? a1 : g == 2 ? a2 : a3;
  out[pbase + lane] = v;
}

extern "C" void kernel_launch(void* const* d_in, const int* in_sizes, int n_in,
                              void* d_out, int out_size, void* d_ws, size_t ws_size,
                              hipStream_t stream) {
  const float* time = (const float*)d_in[0];
  const float* xyz  = (const float*)d_in[1];
  const float* te0  = (const float*)d_in[2];
  const float* te1  = (const float*)d_in[3];
  const float* W0   = (const float*)d_in[4];
  const float* b0   = (const float*)d_in[5];
  const float* W1   = (const float*)d_in[6];
  const float* b1   = (const float*)d_in[7];
  const float* W2   = (const float*)d_in[8];
  const float* b2   = (const float*)d_in[9];
  const float* Wout = (const float*)d_in[10];
  const float* bout = (const float*)d_in[11];
  float* out = (float*)d_out;
  unsigned char* ws = (unsigned char*)d_ws;
  if (ws_size < WS_NEEDED) return;

  pack_weights<<<88, 64, 0, stream>>>(time, te0, te1, W0, W1, W2, Wout, ws);
  mlp_main<<<NPTS / 512, 512, LDS_TOTAL, stream>>>(xyz, b0, b1, b2, bout, ws, out);
}

// Round 10
// 49.226 us; speedup vs baseline: 1.0311x; 1.0311x over previous
//
#include <hip/hip_runtime.h>

typedef _Float16 f16;
typedef __attribute__((ext_vector_type(2))) __fp16 fp16x2;
typedef __attribute__((ext_vector_type(8))) _Float16 f16x8;
typedef __attribute__((ext_vector_type(4))) float f32x4;
typedef __attribute__((ext_vector_type(4))) unsigned int u32x4;

#define NPTS   (16 * 32768)
// packed-weight layout in d_ws (bytes); weights stay in global (L2-resident, ~80KB)
#define W0P_OFF 0
#define W1P_OFF (16 * 1024)
#define W2P_OFF (48 * 1024)
#define WOP_OFF (80 * 1024)
#define FRAGS_BYTES (84 * 1024)
#define TENC_OFF FRAGS_BYTES          // in ws: 16 batches x 16 f32
#define WS_NEEDED (FRAGS_BYTES + 1024)
// LDS: only per-wave transpose scratch. 4 waves x 4KB = 16KB/block.
// 256-thr blocks: residency granularity = 4 waves x ~140 regs (92 VGPR + ~48 AGPR)
// = ~560 regs -> 3 blocks/CU (12 waves, 3/SIMD) vs 512-thr's 1 block (8 waves).
#define LDS_TOTAL (4 * 4096)

// ---------------- pack kernel: weights -> f16 A-operand fragments (W^T) ----------------
// A frag (mt,kt): lane l, elem j <-> W_sw[m = 16mt + (l&15)][k] = W[k][m]
//   layer0 (natural k-map, matches layer-0 B build): k = 32kt + 8*(l>>4) + j
//   layers 1,2,out (chained from D layout):          k = 32kt + 16*(j>>2) + 4*(l>>4) + (j&3)
__global__ void pack_weights(const float* __restrict__ time, const float* __restrict__ te0,
                             const float* __restrict__ te1, const float* __restrict__ W0,
                             const float* __restrict__ W1, const float* __restrict__ W2,
                             const float* __restrict__ Wout, unsigned char* __restrict__ ws) {
  const int bi = blockIdx.x;
  const int l = threadIdx.x;
  const int g = l >> 4, r16 = l & 15;
  if (bi < 84) {
    const float* W; int obase, fi, kt, mt, kmax; bool natural, outcol;
    if (bi < 16)      { W = W0;   fi = bi;      mt = fi >> 1; kt = fi & 1; obase = W0P_OFF; kmax = 55;  natural = true;  outcol = false; }
    else if (bi < 48) { W = W1;   fi = bi - 16; mt = fi >> 2; kt = fi & 3; obase = W1P_OFF; kmax = 128; natural = false; outcol = false; }
    else if (bi < 80) { W = W2;   fi = bi - 48; mt = fi >> 2; kt = fi & 3; obase = W2P_OFF; kmax = 128; natural = false; outcol = false; }
    else              { W = Wout; fi = bi - 80; mt = 0;       kt = fi;     obase = WOP_OFF; kmax = 128; natural = false; outcol = true;  }
    const int m = mt * 16 + r16;
    f16 vals[8] __attribute__((aligned(16)));
#pragma unroll
    for (int j = 0; j < 8; ++j) {
      const int k = natural ? (kt * 32 + g * 8 + j)
                            : (kt * 32 + (j >> 2) * 16 + g * 4 + (j & 3));
      float v = 0.f;
      if (k < kmax) v = outcol ? ((m == 0) ? Wout[k] : 0.f) : W[k * 128 + m];
      vals[j] = (f16)v;
    }
    *(u32x4*)(ws + obase + (fi * 64 + l) * 16) = *(const u32x4*)vals;
  } else {
    // time encoding: 16 batches x 16 dims fp32
    const int idx = (bi - 84) * 64 + l;  // 0..255
    const int b = idx >> 4, d = idx & 15;
    const float t = time[b];
    const float* emb; int L, dd;
    if (d < 8) { emb = te0; L = 5;  dd = d; }
    else       { emb = te1; L = 20; dd = d - 8; }
    const float tL = t * (float)L;
    int i = (int)floorf(tL);
    i = i < 0 ? 0 : (i > L - 1 ? L - 1 : i);
    const float wlo = (float)(i + 1) - tL;
    float v = wlo * emb[i * 8 + dd] + (1.f - wlo) * emb[(i + 1) * 8 + dd];
    if (t >= 1.f) v = emb[L * 8 + dd];
    ((float*)(ws + TENC_OFF))[idx] = v;
  }
}

// ---------------- one swapped hidden layer: D = W_sw(128xK) * Bin(Kx64) ----------------
// A-frags stream from L2 with a 2-deep rotating prefetch across the flattened
// (mtp,kt) step sequence (r8 structure — best measured). Bias loaded at kt==0,
// applied in the kt==KT-1 epilogue (acc zero-init).
template <int KT>
__device__ __forceinline__ void layer_swapped(const unsigned char* __restrict__ wsrc,
                                              const float* __restrict__ bias,
                                              const f16x8 (&Bin)[KT][4], f16x8 (&Bout)[4][4],
                                              int lane) {
  const int g4 = (lane >> 4) * 4;
  f16x8 A0b[3], A1b[3];
  float4 ba, bb;
  f32x4 acc[2][4];
  // prologue: preload steps 0,1
#pragma unroll
  for (int s = 0; s < 2; ++s) {
    const int mtp = s / KT, kt = s % KT;
    A0b[s] = *(const f16x8*)(wsrc + (((2 * mtp)     * KT + kt) * 64 + lane) * 16);
    A1b[s] = *(const f16x8*)(wsrc + (((2 * mtp + 1) * KT + kt) * 64 + lane) * 16);
  }
#pragma unroll
  for (int s = 0; s < 4 * KT; ++s) {
    const int mtp = s / KT, kt = s % KT, cb = s % 3;
    if (kt == 0) {
      ba = *(const float4*)(bias + mtp * 32 + g4);
      bb = *(const float4*)(bias + mtp * 32 + 16 + g4);
#pragma unroll
      for (int nt = 0; nt < 4; ++nt) {
        acc[0][nt] = (f32x4){0.f, 0.f, 0.f, 0.f};
        acc[1][nt] = (f32x4){0.f, 0.f, 0.f, 0.f};
      }
    }
    // prefetch step s+2
    if (s + 2 < 4 * KT) {
      const int mtp2 = (s + 2) / KT, kt2 = (s + 2) % KT, pb = (s + 2) % 3;
      A0b[pb] = *(const f16x8*)(wsrc + (((2 * mtp2)     * KT + kt2) * 64 + lane) * 16);
      A1b[pb] = *(const f16x8*)(wsrc + (((2 * mtp2 + 1) * KT + kt2) * 64 + lane) * 16);
    }
    __builtin_amdgcn_s_setprio(1);
#pragma unroll
    for (int nt = 0; nt < 4; ++nt)
      acc[0][nt] = __builtin_amdgcn_mfma_f32_16x16x32_f16(A0b[cb], Bin[kt][nt], acc[0][nt], 0, 0, 0);
#pragma unroll
    for (int nt = 0; nt < 4; ++nt)
      acc[1][nt] = __builtin_amdgcn_mfma_f32_16x16x32_f16(A1b[cb], Bin[kt][nt], acc[1][nt], 0, 0, 0);
    __builtin_amdgcn_s_setprio(0);
    if (kt == KT - 1) {
      const float* bap = (const float*)&ba;
      const float* bbp = (const float*)&bb;
#pragma unroll
      for (int nt = 0; nt < 4; ++nt) {
        union { fp16x2 h2[4]; f16x8 v; } u;
        u.h2[0] = __builtin_amdgcn_cvt_pkrtz(fmaxf(acc[0][nt][0] + bap[0], 0.f), fmaxf(acc[0][nt][1] + bap[1], 0.f));
        u.h2[1] = __builtin_amdgcn_cvt_pkrtz(fmaxf(acc[0][nt][2] + bap[2], 0.f), fmaxf(acc[0][nt][3] + bap[3], 0.f));
        u.h2[2] = __builtin_amdgcn_cvt_pkrtz(fmaxf(acc[1][nt][0] + bbp[0], 0.f), fmaxf(acc[1][nt][1] + bbp[1], 0.f));
        u.h2[3] = __builtin_amdgcn_cvt_pkrtz(fmaxf(acc[1][nt][2] + bbp[2], 0.f), fmaxf(acc[1][nt][3] + bbp[3], 0.f));
        Bout[mtp][nt] = u.v;
      }
    }
  }
}

// ---------------- fused main kernel: 256 thr (4 waves), weights from L2, prefetch ----------------
// __launch_bounds__(256,2): VGPR budget 2048/8 = 256 — identical per-wave budget to
// r8's (512,1), so codegen should match (92 VGPR). Smaller block = finer residency
// granularity: 3 blocks/CU = 12 waves = 3 waves/SIMD (vs 512-thr's 8 waves).
__global__ void __launch_bounds__(256, 2)
mlp_main(const float* __restrict__ xyz, const float* __restrict__ b0,
         const float* __restrict__ b1, const float* __restrict__ b2,
         const float* __restrict__ bout, const unsigned char* __restrict__ ws,
         float* __restrict__ out) {
  extern __shared__ char lds[];
  const int tid = threadIdx.x;
  const int lane = tid & 63, wv = tid >> 6;
  const int g = lane >> 4, r16 = lane & 15;

  char* scr = lds + wv * 4096;  // per-wave private transpose scratch (32 rows x 128B)
  const float bo = bout[0];

  const int pbase = blockIdx.x * 256 + wv * 64;
  const int p = pbase + lane;

  // ---- 64-dim feature row for own point ----
  f16 feat[64] __attribute__((aligned(16)));
  const float* tb = (const float*)(ws + TENC_OFF) + (blockIdx.x >> 7) * 16;  // batch = p/32768
#pragma unroll
  for (int i = 0; i < 16; ++i) feat[i] = (f16)tb[i];
  const float xs0 = xyz[p * 3], xs1 = xyz[p * 3 + 1], xs2 = xyz[p * 3 + 2];
  const float pcs[3] = {(xs0 + 1.f) * 0.5f, (xs1 + 1.f) * 0.5f, (xs2 + 1.f) * 0.5f};
#pragma unroll
  for (int c = 0; c < 3; ++c) {
    feat[16 + c] = (f16)pcs[c];
    float s = __sinf(pcs[c]), co = __cosf(pcs[c]);
#pragma unroll
    for (int f = 0; f < 6; ++f) {
      feat[19 + f * 3 + c] = (f16)s;
      feat[37 + f * 3 + c] = (f16)co;
      const float s2 = 2.f * s * co, c2 = 1.f - 2.f * s * s;
      s = s2; co = c2;
    }
  }
#pragma unroll
  for (int i = 55; i < 64; ++i) feat[i] = (f16)0.f;

  // ---- transpose via per-wave scratch, two 32-point halves (wave-internal sync) ----
  f16x8 B0[2][4];
#pragma unroll
  for (int h = 0; h < 2; ++h) {
    if ((lane >> 5) == h) {
#pragma unroll
      for (int s = 0; s < 8; ++s)
        *(u32x4*)(scr + (lane & 31) * 128 + ((s ^ (lane & 7)) * 16)) = ((const u32x4*)feat)[s];
    }
    asm volatile("s_waitcnt lgkmcnt(0)" ::: "memory");
#pragma unroll
    for (int kt = 0; kt < 2; ++kt)
#pragma unroll
      for (int nn = 0; nn < 2; ++nn) {
        const int row = nn * 16 + r16;
        B0[kt][h * 2 + nn] = *(const f16x8*)(scr + row * 128 + (((4 * kt + g) ^ (row & 7)) * 16));
      }
    asm volatile("s_waitcnt lgkmcnt(0)" ::: "memory");
  }

  // ---- 3 hidden layers fully in registers, weights streamed from L2 w/ prefetch ----
  f16x8 Bx[4][4], By[4][4];
  layer_swapped<2>(ws + W0P_OFF, b0, B0, Bx, lane);
  layer_swapped<4>(ws + W1P_OFF, b1, Bx, By, lane);
  layer_swapped<4>(ws + W2P_OFF, b2, By, Bx, lane);

  // ---- output layer (M=16 padded, only row 0 real), rotating prefetch ----
  f16x8 Ab[3];
  Ab[0] = *(const f16x8*)(ws + WOP_OFF + (0 * 64 + lane) * 16);
  Ab[1] = *(const f16x8*)(ws + WOP_OFF + (1 * 64 + lane) * 16);
  f32x4 accO[4];
#pragma unroll
  for (int nt = 0; nt < 4; ++nt) accO[nt] = (f32x4){bo, bo, bo, bo};
#pragma unroll
  for (int kt = 0; kt < 4; ++kt) {
    if (kt + 2 < 4)
      Ab[(kt + 2) % 3] = *(const f16x8*)(ws + WOP_OFF + ((kt + 2) * 64 + lane) * 16);
    __builtin_amdgcn_s_setprio(1);
#pragma unroll
    for (int nt = 0; nt < 4; ++nt)
      accO[nt] = __builtin_amdgcn_mfma_f32_16x16x32_f16(Ab[kt % 3], Bx[kt][nt], accO[nt], 0, 0, 0);
    __builtin_amdgcn_s_setprio(0);
  }

  // ---- coalesced store: broadcast row-0 values, one 256B wave store ----
  const float a0 = __shfl(accO[0][0], r16, 64);
  const float a1 = __shfl(accO[1][0], r16, 64);
  const float a2 = __shfl(accO[2][0], r16, 64);
  const float a3 = __shfl(accO[3][0], r16, 64);
  const float v = g == 0 ? a0 : g == 1 ? a1 : g == 2 ? a2 : a3;
  out[pbase + lane] = v;
}

extern "C" void kernel_launch(void* const* d_in, const int* in_sizes, int n_in,
                              void* d_out, int out_size, void* d_ws, size_t ws_size,
                              hipStream_t stream) {
  const float* time = (const float*)d_in[0];
  const float* xyz  = (const float*)d_in[1];
  const float* te0  = (const float*)d_in[2];
  const float* te1  = (const float*)d_in[3];
  const float* W0   = (const float*)d_in[4];
  const float* b0   = (const float*)d_in[5];
  const float* W1   = (const float*)d_in[6];
  const float* b1   = (const float*)d_in[7];
  const float* W2   = (const float*)d_in[8];
  const float* b2   = (const float*)d_in[9];
  const float* Wout = (const float*)d_in[10];
  const float* bout = (const float*)d_in[11];
  float* out = (float*)d_out;
  unsigned char* ws = (unsigned char*)d_ws;
  if (ws_size < WS_NEEDED) return;

  pack_weights<<<88, 64, 0, stream>>>(time, te0, te1, W0, W1, W2, Wout, ws);
  mlp_main<<<NPTS / 256, 256, LDS_TOTAL, stream>>>(xyz, b0, b1, b2, bout, ws, out);
}